// Round 1
// baseline (526.680 us; speedup 1.0000x reference)
//
#include <hip/hip_runtime.h>
#include <hip/hip_bf16.h>
#include <stdint.h>

#define M_DIM 8192
#define K_DIM 512
#define N_DIM 32000

typedef short bf16x8 __attribute__((ext_vector_type(8)));
typedef float f32x4 __attribute__((ext_vector_type(4)));
typedef unsigned short u16;

__device__ __forceinline__ u16 f2bf(float f) {
  union { float f; uint32_t u; } v; v.f = f;
  uint32_t r = (v.u + 0x7fffu + ((v.u >> 16) & 1u)) >> 16;  // RNE
  return (u16)r;
}

// ---------------- Kernel 1: row-l2norm of x -> bf16, one wave per row ----------------
__global__ void k_xnorm(const float* __restrict__ x, u16* __restrict__ xn) {
  int row = (blockIdx.x * blockDim.x + threadIdx.x) >> 6;
  int lane = threadIdx.x & 63;
  const float4* rp = (const float4*)(x + (size_t)row * K_DIM);
  float4 a = rp[lane];
  float4 b = rp[lane + 64];
  float s = a.x*a.x + a.y*a.y + a.z*a.z + a.w*a.w
          + b.x*b.x + b.y*b.y + b.z*b.z + b.w*b.w;
#pragma unroll
  for (int off = 32; off > 0; off >>= 1) s += __shfl_xor(s, off, 64);
  float r = rsqrtf(fmaxf(s, 1e-12f));
  ushort4 o0 = make_ushort4(f2bf(a.x*r), f2bf(a.y*r), f2bf(a.z*r), f2bf(a.w*r));
  ushort4 o1 = make_ushort4(f2bf(b.x*r), f2bf(b.y*r), f2bf(b.z*r), f2bf(b.w*r));
  ushort4* dst = (ushort4*)(xn + (size_t)row * K_DIM);
  dst[lane] = o0;
  dst[lane + 64] = o1;
}

// ---------------- Kernel 2: column sumsq of w -> rsqrt factors ----------------
__global__ void k_wnorm(const float* __restrict__ w, float* __restrict__ cn) {
  int c = blockIdx.x * 256 + threadIdx.x;
  int rg = threadIdx.y;  // 0..3
  const float* p = w + (size_t)rg * 128 * N_DIM + c;
  float s = 0.f;
#pragma unroll 8
  for (int r = 0; r < 128; ++r) {
    float v = p[(size_t)r * N_DIM];
    s = fmaf(v, v, s);
  }
  __shared__ float red[4][256];
  red[rg][threadIdx.x] = s;
  __syncthreads();
  if (rg == 0) {
    float t = red[0][threadIdx.x] + red[1][threadIdx.x]
            + red[2][threadIdx.x] + red[3][threadIdx.x];
    cn[c] = rsqrtf(fmaxf(t, 1e-12f));
  }
}

// ---------------- Kernel 3: transpose + scale + cast: w[512][32000] -> wT[32000][512] bf16 ----------------
__global__ void k_wtrans(const float* __restrict__ w, const float* __restrict__ cn,
                         u16* __restrict__ wT) {
  __shared__ u16 tile[64][68];  // pad: row stride 136 B (8B-aligned, conflict-light)
  int c0 = blockIdx.x * 64;
  int r0 = blockIdx.y * 64;
  int tc = threadIdx.x & 63;
  int tw = threadIdx.x >> 6;  // 0..3
  float scale = cn[c0 + tc];
#pragma unroll
  for (int i = 0; i < 16; ++i) {
    int r = i * 4 + tw;
    float v = w[(size_t)(r0 + r) * N_DIM + c0 + tc];
    tile[tc][r] = f2bf(v * scale);
  }
  __syncthreads();
  int cc = threadIdx.x >> 4;        // 0..15
  int rr = (threadIdx.x & 15) * 4;  // 0..60
#pragma unroll
  for (int i = 0; i < 4; ++i) {
    int c = cc + i * 16;
    ushort4 v = *(const ushort4*)&tile[c][rr];
    *(ushort4*)(wT + (size_t)(c0 + c) * K_DIM + r0 + rr) = v;
  }
}

// ---------------- Kernel 4: GEMM C[M][N] = xn[M][K] * wT[N][K]^T  (bf16 MFMA, fp32 out) ----------------
__global__ __launch_bounds__(256) void k_gemm(const u16* __restrict__ A,
                                              const u16* __restrict__ Bt,
                                              float* __restrict__ C) {
  __shared__ u16 As[128 * 64];  // [row 0..127][k 0..63], linear
  __shared__ u16 Bs[128 * 64];  // [col 0..127][k 0..63], linear

  // XCD-aware swizzle (16000 % 8 == 0 -> bijective simple form)
  int bid = blockIdx.x;
  int cpx = gridDim.x >> 3;
  bid = (bid & 7) * cpx + (bid >> 3);
  int bm = bid / (N_DIM / 128);
  int bn = bid % (N_DIM / 128);

  int t = threadIdx.x;
  int lane = t & 63;
  int w = t >> 6;       // wave 0..3
  int wr = w >> 1;      // 0..1
  int wc = w & 1;       // 0..1

  f32x4 acc[4][4] = {};

  // staging addresses: thread t deposits 16B at LDS elem t*8 (+ i*2048)
  const u16* ag = A + (size_t)(bm * 128 + (t >> 3)) * K_DIM + (t & 7) * 8;
  const u16* bg = Bt + (size_t)(bn * 128 + (t >> 3)) * K_DIM + (t & 7) * 8;
  u16* as_dst = As + t * 8;
  u16* bs_dst = Bs + t * 8;

  for (int kt = 0; kt < K_DIM / 64; ++kt) {
    const u16* agk = ag + kt * 64;
    const u16* bgk = bg + kt * 64;
#pragma unroll
    for (int i = 0; i < 4; ++i) {
      __builtin_amdgcn_global_load_lds(
          (const __attribute__((address_space(1))) void*)(agk + (size_t)i * 32 * K_DIM),
          (__attribute__((address_space(3))) void*)(as_dst + i * 2048), 16, 0, 0);
    }
#pragma unroll
    for (int i = 0; i < 4; ++i) {
      __builtin_amdgcn_global_load_lds(
          (const __attribute__((address_space(1))) void*)(bgk + (size_t)i * 32 * K_DIM),
          (__attribute__((address_space(3))) void*)(bs_dst + i * 2048), 16, 0, 0);
    }
    __syncthreads();  // emits vmcnt(0) drain before barrier

#pragma unroll
    for (int kk = 0; kk < 64; kk += 32) {
      bf16x8 af[4], bfr[4];
#pragma unroll
      for (int m = 0; m < 4; ++m)
        af[m] = *(const bf16x8*)&As[(wr * 64 + m * 16 + (lane & 15)) * 64 + kk + (lane >> 4) * 8];
#pragma unroll
      for (int n = 0; n < 4; ++n)
        bfr[n] = *(const bf16x8*)&Bs[(wc * 64 + n * 16 + (lane & 15)) * 64 + kk + (lane >> 4) * 8];
#pragma unroll
      for (int m = 0; m < 4; ++m)
#pragma unroll
        for (int n = 0; n < 4; ++n)
          acc[m][n] = __builtin_amdgcn_mfma_f32_16x16x32_bf16(af[m], bfr[n], acc[m][n], 0, 0, 0);
    }
    __syncthreads();
  }

  // epilogue: C/D layout col = lane&15, row = (lane>>4)*4 + j   [m89-verified]
  size_t crow0 = (size_t)(bm * 128 + wr * 64 + ((lane >> 4) * 4));
  int ccol0 = bn * 128 + wc * 64 + (lane & 15);
#pragma unroll
  for (int m = 0; m < 4; ++m)
#pragma unroll
    for (int n = 0; n < 4; ++n)
#pragma unroll
      for (int j = 0; j < 4; ++j)
        C[(crow0 + m * 16 + j) * N_DIM + (size_t)(ccol0 + n * 16)] = acc[m][n][j];
}

// ---------------- launch ----------------
extern "C" void kernel_launch(void* const* d_in, const int* in_sizes, int n_in,
                              void* d_out, int out_size, void* d_ws, size_t ws_size,
                              hipStream_t stream) {
  const float* x = (const float*)d_in[0];   // [8192, 512]
  const float* w = (const float*)d_in[1];   // [512, 32000]
  float* out = (float*)d_out;               // [8192, 32000]

  char* ws = (char*)d_ws;
  float* cn = (float*)ws;                                  // 32000 f32
  u16* xn = (u16*)(ws + 131072);                           // 8192*512 bf16 (8 MB)
  u16* wT = (u16*)(ws + 131072 + (size_t)M_DIM * K_DIM * 2); // 32000*512 bf16 (32.8 MB)

  k_xnorm<<<M_DIM / 4, 256, 0, stream>>>(x, xn);
  k_wnorm<<<N_DIM / 256, dim3(256, 4), 0, stream>>>(w, cn);
  k_wtrans<<<dim3(N_DIM / 64, K_DIM / 64), 256, 0, stream>>>(w, cn, wT);
  k_gemm<<<(M_DIM / 128) * (N_DIM / 128), 256, 0, stream>>>(xn, wT, out);
}

// Round 2
// 409.402 us; speedup vs baseline: 1.2865x; 1.2865x over previous
//
#include <hip/hip_runtime.h>
#include <hip/hip_bf16.h>
#include <stdint.h>

#define M_DIM 8192
#define K_DIM 512
#define N_DIM 32000

typedef short bf16x8 __attribute__((ext_vector_type(8)));
typedef float f32x4 __attribute__((ext_vector_type(4)));
typedef unsigned short u16;

__device__ __forceinline__ u16 f2bf(float f) {
  union { float f; uint32_t u; } v; v.f = f;
  uint32_t r = (v.u + 0x7fffu + ((v.u >> 16) & 1u)) >> 16;  // RNE
  return (u16)r;
}

// ---------------- Kernel 1: row-l2norm of x -> bf16, one wave per row ----------------
__global__ void k_xnorm(const float* __restrict__ x, u16* __restrict__ xn) {
  int row = (blockIdx.x * blockDim.x + threadIdx.x) >> 6;
  int lane = threadIdx.x & 63;
  const float4* rp = (const float4*)(x + (size_t)row * K_DIM);
  float4 a = rp[lane];
  float4 b = rp[lane + 64];
  float s = a.x*a.x + a.y*a.y + a.z*a.z + a.w*a.w
          + b.x*b.x + b.y*b.y + b.z*b.z + b.w*b.w;
#pragma unroll
  for (int off = 32; off > 0; off >>= 1) s += __shfl_xor(s, off, 64);
  float r = rsqrtf(fmaxf(s, 1e-12f));
  ushort4 o0 = make_ushort4(f2bf(a.x*r), f2bf(a.y*r), f2bf(a.z*r), f2bf(a.w*r));
  ushort4 o1 = make_ushort4(f2bf(b.x*r), f2bf(b.y*r), f2bf(b.z*r), f2bf(b.w*r));
  ushort4* dst = (ushort4*)(xn + (size_t)row * K_DIM);
  dst[lane] = o0;
  dst[lane + 64] = o1;
}

// ---------------- Kernel 2: column sumsq of w -> rsqrt factors ----------------
__global__ void k_wnorm(const float* __restrict__ w, float* __restrict__ cn) {
  int c = blockIdx.x * 256 + threadIdx.x;
  int rg = threadIdx.y;  // 0..3
  const float* p = w + (size_t)rg * 128 * N_DIM + c;
  float s = 0.f;
#pragma unroll 8
  for (int r = 0; r < 128; ++r) {
    float v = p[(size_t)r * N_DIM];
    s = fmaf(v, v, s);
  }
  __shared__ float red[4][256];
  red[rg][threadIdx.x] = s;
  __syncthreads();
  if (rg == 0) {
    float t = red[0][threadIdx.x] + red[1][threadIdx.x]
            + red[2][threadIdx.x] + red[3][threadIdx.x];
    cn[c] = rsqrtf(fmaxf(t, 1e-12f));
  }
}

// ---------------- Kernel 3: transpose + scale + cast: w[512][32000] -> wT[32000][512] bf16 ----------------
__global__ void k_wtrans(const float* __restrict__ w, const float* __restrict__ cn,
                         u16* __restrict__ wT) {
  __shared__ u16 tile[64][68];
  int c0 = blockIdx.x * 64;
  int r0 = blockIdx.y * 64;
  int tc = threadIdx.x & 63;
  int tw = threadIdx.x >> 6;  // 0..3
  float scale = cn[c0 + tc];
#pragma unroll
  for (int i = 0; i < 16; ++i) {
    int r = i * 4 + tw;
    float v = w[(size_t)(r0 + r) * N_DIM + c0 + tc];
    tile[tc][r] = f2bf(v * scale);
  }
  __syncthreads();
  int cc = threadIdx.x >> 4;        // 0..15
  int rr = (threadIdx.x & 15) * 4;  // 0..60
#pragma unroll
  for (int i = 0; i < 4; ++i) {
    int c = cc + i * 16;
    ushort4 v = *(const ushort4*)&tile[c][rr];
    *(ushort4*)(wT + (size_t)(c0 + c) * K_DIM + r0 + rr) = v;
  }
}

// ---------------- Kernel 4: 256x256 GEMM, 8 waves, 4-phase K-tiles, swizzled LDS ----------------
// C[M][N] = xn[M][K] * wT[N][K]^T, bf16 MFMA, fp32 out.
__global__ __launch_bounds__(512, 2) void k_gemm(const u16* __restrict__ A,
                                                 const u16* __restrict__ Bt,
                                                 float* __restrict__ C) {
  // per buffer: A tile [256][64] at 0, B tile [256][64] at 16384 (elements)
  __shared__ u16 sm[2][32768];  // 128 KiB total
  constexpr int BOFF = 16384;

  // XCD swizzle: 4000 blocks, 4000 % 8 == 0 -> bijective
  int bid = blockIdx.x;
  bid = (bid & 7) * 500 + (bid >> 3);
  const int bm = bid / 125;
  const int bn = bid % 125;

  const int t = threadIdx.x;
  const int lane = t & 63;
  const int w = t >> 6;     // wave 0..7
  const int wr = w >> 2;    // 0..1  (M half: 128 rows)
  const int wc = w & 3;     // 0..3  (N strip: 64 cols)
  const int la = lane & 15;
  const int lk = lane >> 4; // 0..3
  const int rx = la & 7;    // row&7 for all fragment rows this lane touches
  const int s0 = ((0 + lk) ^ rx) * 8;  // swizzled elem-col, kk=0
  const int s1 = ((4 + lk) ^ rx) * 8;  // swizzled elem-col, kk=32

  f32x4 acc[8][4] = {};

  // staging geometry: instr i covers rows i*64 + (t>>3); lane fetches global
  // slot (t&7)^(row&7) so LINEAR LDS dest ends up swizzle-stored (rule #21).
  const int srow = t >> 3;
  const int sgl = ((t & 7) ^ (srow & 7)) * 8;  // pre-swizzled global elem col
  const u16* ag = A  + (size_t)(bm * 256 + srow) * K_DIM + sgl;
  const u16* bg = Bt + (size_t)(bn * 256 + srow) * K_DIM + sgl;
  const int ldst = srow * 64 + (t & 7) * 8;    // linear LDS elem offset

  // prologue: stage tile 0 into buf 0
#pragma unroll
  for (int i = 0; i < 4; ++i)
    __builtin_amdgcn_global_load_lds(
        (const __attribute__((address_space(1))) void*)(ag + (size_t)i * 64 * K_DIM),
        (__attribute__((address_space(3))) void*)&sm[0][i * 4096 + ldst], 16, 0, 0);
#pragma unroll
  for (int i = 0; i < 4; ++i)
    __builtin_amdgcn_global_load_lds(
        (const __attribute__((address_space(1))) void*)(bg + (size_t)i * 64 * K_DIM),
        (__attribute__((address_space(3))) void*)&sm[0][BOFF + i * 4096 + ldst], 16, 0, 0);
  __syncthreads();

  const int arow0 = (wr * 128 + la) * 64;  // A LDS row base (elem), + m*16*64
  const int brow0 = (wc * 64 + la) * 64;   // B LDS row base (elem), + n*16*64

  for (int kt = 0; kt < 8; ++kt) {
    const int cur = kt & 1;
    const int nxt = cur ^ 1;
    const bool pf = (kt + 1) < 8;
    const int ko = (kt + 1) * 64;

    bf16x8 bf[4][2];

    // ---- phase 1: m = 0,1 ; read all B frags; stage next A ----
    {
#pragma unroll
      for (int n = 0; n < 4; ++n) {
        bf[n][0] = *(const bf16x8*)&sm[cur][BOFF + brow0 + n * 1024 + s0];
        bf[n][1] = *(const bf16x8*)&sm[cur][BOFF + brow0 + n * 1024 + s1];
      }
      bf16x8 af[2][2];
#pragma unroll
      for (int m = 0; m < 2; ++m) {
        af[m][0] = *(const bf16x8*)&sm[cur][arow0 + m * 1024 + s0];
        af[m][1] = *(const bf16x8*)&sm[cur][arow0 + m * 1024 + s1];
      }
      if (pf) {
#pragma unroll
        for (int i = 0; i < 4; ++i)
          __builtin_amdgcn_global_load_lds(
              (const __attribute__((address_space(1))) void*)(ag + (size_t)i * 64 * K_DIM + ko),
              (__attribute__((address_space(3))) void*)&sm[nxt][i * 4096 + ldst], 16, 0, 0);
      }
      __builtin_amdgcn_s_barrier();
      asm volatile("s_waitcnt lgkmcnt(0)" ::: "memory");
      __builtin_amdgcn_sched_barrier(0);
      __builtin_amdgcn_s_setprio(1);
#pragma unroll
      for (int m = 0; m < 2; ++m)
#pragma unroll
        for (int n = 0; n < 4; ++n) {
          acc[m][n] = __builtin_amdgcn_mfma_f32_16x16x32_bf16(af[m][0], bf[n][0], acc[m][n], 0, 0, 0);
          acc[m][n] = __builtin_amdgcn_mfma_f32_16x16x32_bf16(af[m][1], bf[n][1], acc[m][n], 0, 0, 0);
        }
      __builtin_amdgcn_s_setprio(0);
      __builtin_amdgcn_s_barrier();
    }

    // ---- phases 2..4: m = 2p..2p+1 ; phase 2 stages next B ----
#pragma unroll
    for (int p = 1; p < 4; ++p) {
      bf16x8 af[2][2];
#pragma unroll
      for (int m = 0; m < 2; ++m) {
        af[m][0] = *(const bf16x8*)&sm[cur][arow0 + (p * 2 + m) * 1024 + s0];
        af[m][1] = *(const bf16x8*)&sm[cur][arow0 + (p * 2 + m) * 1024 + s1];
      }
      if (p == 1 && pf) {
#pragma unroll
        for (int i = 0; i < 4; ++i)
          __builtin_amdgcn_global_load_lds(
              (const __attribute__((address_space(1))) void*)(bg + (size_t)i * 64 * K_DIM + ko),
              (__attribute__((address_space(3))) void*)&sm[nxt][BOFF + i * 4096 + ldst], 16, 0, 0);
      }
      __builtin_amdgcn_s_barrier();
      asm volatile("s_waitcnt lgkmcnt(0)" ::: "memory");
      __builtin_amdgcn_sched_barrier(0);
      __builtin_amdgcn_s_setprio(1);
#pragma unroll
      for (int m = 0; m < 2; ++m)
#pragma unroll
        for (int n = 0; n < 4; ++n) {
          acc[p * 2 + m][n] = __builtin_amdgcn_mfma_f32_16x16x32_bf16(af[m][0], bf[n][0], acc[p * 2 + m][n], 0, 0, 0);
          acc[p * 2 + m][n] = __builtin_amdgcn_mfma_f32_16x16x32_bf16(af[m][1], bf[n][1], acc[p * 2 + m][n], 0, 0, 0);
        }
      __builtin_amdgcn_s_setprio(0);
      if (p < 3) __builtin_amdgcn_s_barrier();
    }

    __syncthreads();  // tile boundary: drains vmcnt (next buffer staged) + barrier
  }

  // epilogue: C/D layout col = la, row = lk*4 + j  [m89-verified]
  const size_t crow0 = (size_t)bm * 256 + wr * 128 + lk * 4;
  const int ccol0 = bn * 256 + wc * 64 + la;
#pragma unroll
  for (int m = 0; m < 8; ++m)
#pragma unroll
    for (int j = 0; j < 4; ++j) {
      float* cp = C + (crow0 + m * 16 + j) * N_DIM + ccol0;
#pragma unroll
      for (int n = 0; n < 4; ++n) cp[n * 16] = acc[m][n][j];
    }
}

// ---------------- launch ----------------
extern "C" void kernel_launch(void* const* d_in, const int* in_sizes, int n_in,
                              void* d_out, int out_size, void* d_ws, size_t ws_size,
                              hipStream_t stream) {
  const float* x = (const float*)d_in[0];   // [8192, 512]
  const float* w = (const float*)d_in[1];   // [512, 32000]
  float* out = (float*)d_out;               // [8192, 32000]

  char* ws = (char*)d_ws;
  float* cn = (float*)ws;                                    // 32000 f32
  u16* xn = (u16*)(ws + 131072);                             // 8192*512 bf16
  u16* wT = (u16*)(ws + 131072 + (size_t)M_DIM * K_DIM * 2); // 32000*512 bf16

  k_xnorm<<<M_DIM / 4, 256, 0, stream>>>(x, xn);
  k_wnorm<<<N_DIM / 256, dim3(256, 4), 0, stream>>>(w, cn);
  k_wtrans<<<dim3(N_DIM / 64, K_DIM / 64), 256, 0, stream>>>(w, cn, wT);
  k_gemm<<<(M_DIM / 256) * (N_DIM / 256), 512, 0, stream>>>(xn, wT, out);
}